// Round 3
// baseline (2997.871 us; speedup 1.0000x reference)
//
#include <hip/hip_runtime.h>
#include <stdint.h>
#include <math.h>

#define HID 64
#define DIN 128
#define DOUT 40
#define N_LAYERS 8
#define NCHUNK 8
#define CF 8   // features per chunk

static inline int cdiv(int a, int b) { return (a + b - 1) / b; }

// ---------- edge-index layout detection (int32 vs int64 storage) ----------
__global__ void detect_i64(const uint32_t* __restrict__ ei, int* __restrict__ flag) {
    int t = threadIdx.x;
    uint32_t w = ei[2 * t + 1];
    unsigned long long nz = __ballot(w != 0u);
    if (t == 0) *flag = (nz == 0ull) ? 1 : 0;
}

__device__ __forceinline__ int edge_src(const uint32_t* ei, int is64, int E, int e) {
    return is64 ? (int)ei[2 * e] : (int)ei[e];
}
__device__ __forceinline__ int edge_dst(const uint32_t* ei, int is64, int E, int e) {
    return is64 ? (int)ei[2 * (size_t)E + 2 * e] : (int)ei[(size_t)E + e];
}

// ---------- CSR construction ----------
__global__ void init_cnt(int* __restrict__ cnt, int n) {
    int v = blockIdx.x * blockDim.x + threadIdx.x;
    if (v < n) cnt[v] = 0;
}

__global__ void count_deg(const uint32_t* __restrict__ ei, const int* __restrict__ flag,
                          int* __restrict__ cnt, int E) {
    int e = blockIdx.x * blockDim.x + threadIdx.x;
    if (e >= E) return;
    int is64 = *flag;
    atomicAdd(&cnt[edge_dst(ei, is64, E, e)], 1);
}

__global__ void scan1(const int* __restrict__ cnt, int* __restrict__ row_start,
                      int* __restrict__ blocksum, int n) {
    __shared__ int sh[256];
    int t = threadIdx.x;
    int v = blockIdx.x * 256 + t;
    int val = (v < n) ? cnt[v] : 0;
    sh[t] = val;
    __syncthreads();
    for (int o = 1; o < 256; o <<= 1) {
        int y = (t >= o) ? sh[t - o] : 0;
        __syncthreads();
        sh[t] += y;
        __syncthreads();
    }
    if (v < n) row_start[v] = sh[t] - val;
    if (t == 255) blocksum[blockIdx.x] = sh[255];
}

__global__ void scan2(int* __restrict__ blocksum, int nb) {
    __shared__ int sh[512];
    int t = threadIdx.x;
    int val = (t < nb) ? blocksum[t] : 0;
    sh[t] = val;
    __syncthreads();
    for (int o = 1; o < 512; o <<= 1) {
        int y = (t >= o) ? sh[t - o] : 0;
        __syncthreads();
        sh[t] += y;
        __syncthreads();
    }
    if (t < nb) blocksum[t] = sh[t] - val;
}

__global__ void scan3(int* __restrict__ row_start, const int* __restrict__ blocksum,
                      int* __restrict__ cursor, int n) {
    int v = blockIdx.x * 256 + threadIdx.x;
    if (v < n) {
        row_start[v] += blocksum[v >> 8];
        cursor[v] = 0;
    }
}

__global__ void compute_dinv(const int* __restrict__ cnt, float* __restrict__ dinv, int n) {
    int v = blockIdx.x * blockDim.x + threadIdx.x;
    if (v < n) dinv[v] = rsqrtf((float)(cnt[v] + 1));
}

__global__ void scatter_edges(const uint32_t* __restrict__ ei, const int* __restrict__ flag,
                              const int* __restrict__ row_start, int* __restrict__ cursor,
                              int* __restrict__ csr_src, int E) {
    int e = blockIdx.x * blockDim.x + threadIdx.x;
    if (e >= E) return;
    int is64 = *flag;
    int s = edge_src(ei, is64, E, e);
    int d = edge_dst(ei, is64, E, e);
    int pos = row_start[d] + atomicAdd(&cursor[d], 1);
    csr_src[pos] = s;
}

// ---------- h0 = relu(x @ W1 + b1); hp = dinv * h0  (both chunk-major [8][N][8]) ----
#define MLPIN_NB 8
__global__ void mlp_in_reg(const float* __restrict__ x, const float* __restrict__ W1,
                           const float* __restrict__ b1, const float* __restrict__ dinv,
                           float* __restrict__ hp, float* __restrict__ h0, int n) {
    __shared__ float part[MLPIN_NB * 256];
    int t = threadIdx.x;
    int f = t & 63, wv = t >> 6;
    size_t n8 = (size_t)n * CF;
    float wreg[32];
#pragma unroll
    for (int kk = 0; kk < 32; kk++) wreg[kk] = W1[(32 * wv + kk) * HID + f];
    int ntiles = (n + MLPIN_NB - 1) / MLPIN_NB;
    for (int tile = blockIdx.x; tile < ntiles; tile += gridDim.x) {
        int node0 = tile * MLPIN_NB;
#pragma unroll
        for (int nn = 0; nn < MLPIN_NB; nn++) {
            int node = node0 + nn;
            float partial = 0.f;
            if (node < n) {
                const float4* xr = (const float4*)(x + (size_t)node * DIN + 32 * wv);
#pragma unroll
                for (int q = 0; q < 8; q++) {
                    float4 xv = xr[q];
                    partial += xv.x * wreg[4 * q] + xv.y * wreg[4 * q + 1] +
                               xv.z * wreg[4 * q + 2] + xv.w * wreg[4 * q + 3];
                }
            }
            part[nn * 256 + wv * 64 + f] = partial;
        }
        __syncthreads();
#pragma unroll
        for (int r = 0; r < (MLPIN_NB * 64) / 256; r++) {
            int idx = r * 256 + t;
            int nn = idx >> 6, f2 = idx & 63;
            int node = node0 + nn;
            if (node < n) {
                float s = part[nn * 256 + f2] + part[nn * 256 + 64 + f2] +
                          part[nn * 256 + 128 + f2] + part[nn * 256 + 192 + f2] + b1[f2];
                float val = fmaxf(s, 0.f);
                size_t dst = (size_t)(f2 >> 3) * n8 + (size_t)node * CF + (f2 & 7);
                h0[dst] = val;
                hp[dst] = val * dinv[node];
            }
        }
        __syncthreads();
    }
}

// ---------- chunk-pinned SpMM: out_c = 0.9*dv*(self+agg) + 0.1*h0_c ----------
// chunk c = blockIdx%8 -> pinned to one XCD (round-robin dispatch); the 3.2 MB
// feature slice stays resident in that XCD's 4 MB L2.
// lane = (edge-group g = lane>>3) x (feat f = lane&7)
__global__ void spmm_chunk(const float* __restrict__ hp, const float* __restrict__ h0,
                           const float* __restrict__ dinv,
                           const int* __restrict__ row_start, const int* __restrict__ cnt,
                           const int* __restrict__ csr_src,
                           float* __restrict__ out, int n) {
    int c = blockIdx.x & 7;
    int stripe = blockIdx.x >> 3;
    int nstripes = gridDim.x >> 3;
    int lane = threadIdx.x & 63;
    int wv = threadIdx.x >> 6;
    int f = lane & 7, g = lane >> 3;
    size_t n8 = (size_t)n * CF;
    const float* base = hp + (size_t)c * n8;
    const float* h0c  = h0 + (size_t)c * n8;
    float*       outc = out + (size_t)c * n8;
    for (int v = stripe * 4 + wv; v < n; v += nstripes * 4) {
        int j = row_start[v];
        int end = j + cnt[v];
        float acc = 0.f;
        int e = j + g;
        if (e < end) {
            int s = __builtin_nontemporal_load(&csr_src[e]);   // stream: don't pollute L2
            for (e += 8; e < end; e += 8) {
                int s_next = __builtin_nontemporal_load(&csr_src[e]);
                acc += base[(size_t)s * CF + f];               // hot: L2-resident chunk
                s = s_next;
            }
            acc += base[(size_t)s * CF + f];
        }
        // combine the 8 edge-groups (same f, different g): butterfly over g bits
        acc += __shfl_xor(acc, 8);
        acc += __shfl_xor(acc, 16);
        acc += __shfl_xor(acc, 32);
        if (g == 0) {
            float dv = dinv[v];
            float self = base[(size_t)v * CF + f];
            float o = 0.9f * dv * (acc + self) +
                      0.1f * __builtin_nontemporal_load(&h0c[(size_t)v * CF + f]);
            __builtin_nontemporal_store(o, &outc[(size_t)v * CF + f]);
        }
    }
}

// ---------- dense: hpn = (dinv*)? relu((1-beta)*out + beta*(out @ W)) ----------
// chunk-major in/out; LDS row tile + float4 broadcast reads (no shfl dot)
__global__ void dense_layer(const float* __restrict__ outc, const float* __restrict__ W,
                            const float* __restrict__ dinv, float beta, int scale_out,
                            float* __restrict__ hpn, int n) {
    __shared__ __align__(16) float os[32 * HID];
    int t = threadIdx.x;
    int f = t & 63, wv = t >> 6;
    size_t n8 = (size_t)n * CF;
    float wc[64];
#pragma unroll
    for (int k = 0; k < 64; k++) wc[k] = W[k * HID + f];
    int ntiles = (n + 31) / 32;
    for (int tile = blockIdx.x; tile < ntiles; tile += gridDim.x) {
        int node0 = tile * 32;
        for (int i = t; i < 32 * HID; i += 256) {
            int nloc = i >> 6, cf = i & 63;
            int node = node0 + nloc;
            os[i] = (node < n)
                ? outc[(size_t)(cf >> 3) * n8 + (size_t)node * CF + (cf & 7)] : 0.f;
        }
        __syncthreads();
        const float4* os4 = (const float4*)os;
#pragma unroll
        for (int k = 0; k < 8; k++) {
            int nloc = wv + 4 * k;
            int node = node0 + nloc;
            if (node < n) {
                float dot = 0.f;
#pragma unroll
                for (int q = 0; q < 16; q++) {
                    float4 o4 = os4[nloc * 16 + q];
                    dot += o4.x * wc[4 * q] + o4.y * wc[4 * q + 1] +
                           o4.z * wc[4 * q + 2] + o4.w * wc[4 * q + 3];
                }
                float o = os[nloc * HID + f];
                float val = fmaxf((1.f - beta) * o + beta * dot, 0.f);
                if (scale_out) val *= dinv[node];
                hpn[(size_t)(f >> 3) * n8 + (size_t)node * CF + (f & 7)] = val;
            }
        }
        __syncthreads();
    }
}

// ---------- y = h @ W2 + b2  (h chunk-major) ----------
__global__ void mlp_out(const float* __restrict__ h, const float* __restrict__ W2,
                        const float* __restrict__ b2, float* __restrict__ y, int n) {
    __shared__ float hs[32 * HID];
    __shared__ float W2s[HID * DOUT];
    __shared__ float b2s[DOUT];
    int t = threadIdx.x;
    size_t n8 = (size_t)n * CF;
    for (int i = t; i < HID * DOUT; i += 256) W2s[i] = W2[i];
    if (t < DOUT) b2s[t] = b2[t];
    int node0 = blockIdx.x * 32;
    for (int i = t; i < 32 * HID; i += 256) {
        int nloc = i >> 6, cf = i & 63;
        int node = node0 + nloc;
        hs[i] = (node < n)
            ? h[(size_t)(cf >> 3) * n8 + (size_t)node * CF + (cf & 7)] : 0.f;
    }
    __syncthreads();
    for (int idx = t; idx < 32 * DOUT; idx += 256) {
        int nloc = idx / DOUT, fo = idx % DOUT;
        int node = node0 + nloc;
        if (node >= n) continue;
        float dot = b2s[fo];
#pragma unroll 8
        for (int k = 0; k < HID; k++) dot += hs[nloc * HID + k] * W2s[k * DOUT + fo];
        y[(size_t)node * DOUT + fo] = dot;
    }
}

extern "C" void kernel_launch(void* const* d_in, const int* in_sizes, int n_in,
                              void* d_out, int out_size, void* d_ws, size_t ws_size,
                              hipStream_t stream) {
    const float*    x     = (const float*)d_in[0];
    const uint32_t* ei    = (const uint32_t*)d_in[1];
    const float*    W1    = (const float*)d_in[2];
    const float*    b1    = (const float*)d_in[3];
    const float*    convw = (const float*)d_in[4];
    const float*    W2    = (const float*)d_in[5];
    const float*    b2    = (const float*)d_in[6];
    float*          y     = (float*)d_out;

    int N = in_sizes[0] / DIN;
    int E = in_sizes[1] / 2;

    char* ws = (char*)d_ws;
    size_t off = 0;
    auto alloc = [&](size_t bytes) -> char* {
        char* p = ws + off;
        off = (off + bytes + 255) & ~(size_t)255;
        return p;
    };
    int*   flag      = (int*)alloc(4);
    int*   cnt       = (int*)alloc((size_t)N * 4);
    int*   row_start = (int*)alloc((size_t)N * 4);
    int*   cursor    = (int*)alloc((size_t)N * 4);
    float* dinv      = (float*)alloc((size_t)N * 4);
    int*   blocksum  = (int*)alloc(512 * 4);
    int*   csr_src   = (int*)alloc((size_t)E * 4);
    float* h0        = (float*)alloc((size_t)N * HID * 4);
    float* hpA       = (float*)alloc((size_t)N * HID * 4);
    float* hpB       = (float*)alloc((size_t)N * HID * 4);
    float* outc     = (float*)alloc((size_t)N * HID * 4);

    detect_i64<<<1, 64, 0, stream>>>(ei, flag);
    init_cnt<<<cdiv(N, 256), 256, 0, stream>>>(cnt, N);
    count_deg<<<cdiv(E, 256), 256, 0, stream>>>(ei, flag, cnt, E);
    int nb = cdiv(N, 256);
    scan1<<<nb, 256, 0, stream>>>(cnt, row_start, blocksum, N);
    scan2<<<1, 512, 0, stream>>>(blocksum, nb);
    scan3<<<cdiv(N, 256), 256, 0, stream>>>(row_start, blocksum, cursor, N);
    compute_dinv<<<cdiv(N, 256), 256, 0, stream>>>(cnt, dinv, N);
    scatter_edges<<<cdiv(E, 256), 256, 0, stream>>>(ei, flag, row_start, cursor, csr_src, E);

    int mlpin_grid = min(1024, cdiv(N, MLPIN_NB));
    mlp_in_reg<<<mlpin_grid, 256, 0, stream>>>(x, W1, b1, dinv, hpA, h0, N);

    float* cur = hpA;
    float* nxt = hpB;
    for (int i = 0; i < N_LAYERS; i++) {
        float beta = logf(0.5f / (float)(i + 1) + 1.f);
        int scale_out = (i < N_LAYERS - 1) ? 1 : 0;
        spmm_chunk<<<2048, 256, 0, stream>>>(cur, h0, dinv, row_start, cnt, csr_src,
                                             outc, N);
        dense_layer<<<2048, 256, 0, stream>>>(outc, convw + (size_t)i * HID * HID,
                                              dinv, beta, scale_out, nxt, N);
        float* tmp = cur; cur = nxt; nxt = tmp;
    }
    mlp_out<<<cdiv(N, 32), 256, 0, stream>>>(cur, W2, b2, y, N);
}

// Round 4
// 1374.715 us; speedup vs baseline: 2.1807x; 2.1807x over previous
//
#include <hip/hip_runtime.h>
#include <stdint.h>
#include <math.h>

#define HID 64
#define DIN 128
#define DOUT 40
#define N_LAYERS 8

static inline int cdiv(int a, int b) { return (a + b - 1) / b; }

// ---------- edge-index layout detection (int32 vs int64 storage) ----------
__global__ void detect_i64(const uint32_t* __restrict__ ei, int* __restrict__ flag) {
    int t = threadIdx.x;
    uint32_t w = ei[2 * t + 1];
    unsigned long long nz = __ballot(w != 0u);
    if (t == 0) *flag = (nz == 0ull) ? 1 : 0;
}

__device__ __forceinline__ int edge_src(const uint32_t* ei, int is64, int E, int e) {
    return is64 ? (int)ei[2 * e] : (int)ei[e];
}
__device__ __forceinline__ int edge_dst(const uint32_t* ei, int is64, int E, int e) {
    return is64 ? (int)ei[2 * (size_t)E + 2 * e] : (int)ei[(size_t)E + e];
}

// ---------- CSR construction (split-phase: ticket in count pass) ----------
__global__ void init_cnt(int* __restrict__ cnt, int n) {
    int v = blockIdx.x * blockDim.x + threadIdx.x;
    if (v < n) cnt[v] = 0;
}

// pw[e] = position of edge e within its dst bucket (atomic ticket)
__global__ void count_pos(const uint32_t* __restrict__ ei, const int* __restrict__ flag,
                          int* __restrict__ cnt, int* __restrict__ pw, int E) {
    int e = blockIdx.x * blockDim.x + threadIdx.x;
    if (e >= E) return;
    int is64 = *flag;
    int d = edge_dst(ei, is64, E, e);
    pw[e] = atomicAdd(&cnt[d], 1);
}

__global__ void scan1(const int* __restrict__ cnt, int* __restrict__ row_start,
                      int* __restrict__ blocksum, int n) {
    __shared__ int sh[256];
    int t = threadIdx.x;
    int v = blockIdx.x * 256 + t;
    int val = (v < n) ? cnt[v] : 0;
    sh[t] = val;
    __syncthreads();
    for (int o = 1; o < 256; o <<= 1) {
        int y = (t >= o) ? sh[t - o] : 0;
        __syncthreads();
        sh[t] += y;
        __syncthreads();
    }
    if (v < n) row_start[v] = sh[t] - val;
    if (t == 255) blocksum[blockIdx.x] = sh[255];
}

__global__ void scan2(int* __restrict__ blocksum, int nb) {
    __shared__ int sh[512];
    int t = threadIdx.x;
    int val = (t < nb) ? blocksum[t] : 0;
    sh[t] = val;
    __syncthreads();
    for (int o = 1; o < 512; o <<= 1) {
        int y = (t >= o) ? sh[t - o] : 0;
        __syncthreads();
        sh[t] += y;
        __syncthreads();
    }
    if (t < nb) blocksum[t] = sh[t] - val;
}

__global__ void scan3(int* __restrict__ row_start, const int* __restrict__ blocksum, int n) {
    int v = blockIdx.x * 256 + threadIdx.x;
    if (v < n) row_start[v] += blocksum[v >> 8];
}

__global__ void compute_dinv(const int* __restrict__ cnt, float* __restrict__ dinv, int n) {
    int v = blockIdx.x * blockDim.x + threadIdx.x;
    if (v < n) dinv[v] = rsqrtf((float)(cnt[v] + 1));
}

// plain random 4B write, no atomic (ticket already assigned)
__global__ void scatter_pos(const uint32_t* __restrict__ ei, const int* __restrict__ flag,
                            const int* __restrict__ row_start, const int* __restrict__ pw,
                            int* __restrict__ csr_src, int E) {
    int e = blockIdx.x * blockDim.x + threadIdx.x;
    if (e >= E) return;
    int is64 = *flag;
    int s = edge_src(ei, is64, E, e);
    int d = edge_dst(ei, is64, E, e);
    csr_src[row_start[d] + pw[e]] = s;
}

// ---------- h0 = relu(x @ W1 + b1); hp = dinv * h0  (row-major [N][64]) ----------
#define MT 16
__global__ void mlp_in_v3(const float* __restrict__ x, const float* __restrict__ W1,
                          const float* __restrict__ b1, const float* __restrict__ dinv,
                          float* __restrict__ hp, float* __restrict__ h0, int n) {
    __shared__ __align__(16) float xs[MT * DIN];   // 8 KB, coalesced-staged
    __shared__ float part[MT * 256];               // 16 KB partial sums
    int t = threadIdx.x;
    int f = t & 63, wv = t >> 6;
    float wreg[32];
#pragma unroll
    for (int kk = 0; kk < 32; kk++) wreg[kk] = W1[(32 * wv + kk) * HID + f];
    int ntiles = (n + MT - 1) / MT;
    for (int tile = blockIdx.x; tile < ntiles; tile += gridDim.x) {
        int node0 = tile * MT;
        // coalesced stage: each lane loads distinct float4
        const float4* xsrc = (const float4*)(x + (size_t)node0 * DIN);
        float4* xd = (float4*)xs;
        int lim = (min(MT, n - node0) * DIN) >> 2;
#pragma unroll
        for (int r = 0; r < (MT * DIN / 4) / 256; r++) {
            int i = r * 256 + t;
            xd[i] = (i < lim) ? xsrc[i] : make_float4(0.f, 0.f, 0.f, 0.f);
        }
        __syncthreads();
        const float4* xs4 = (const float4*)xs;
#pragma unroll
        for (int nn = 0; nn < MT; nn++) {
            float partial = 0.f;
#pragma unroll
            for (int q = 0; q < 8; q++) {
                float4 xv = xs4[nn * (DIN / 4) + wv * 8 + q];  // LDS broadcast
                partial += xv.x * wreg[4 * q] + xv.y * wreg[4 * q + 1] +
                           xv.z * wreg[4 * q + 2] + xv.w * wreg[4 * q + 3];
            }
            part[nn * 256 + wv * 64 + f] = partial;
        }
        __syncthreads();
#pragma unroll
        for (int r = 0; r < (MT * 64) / 256; r++) {
            int idx = r * 256 + t;
            int nn = idx >> 6, f2 = idx & 63;
            int node = node0 + nn;
            if (node < n) {
                float s = part[nn * 256 + f2] + part[nn * 256 + 64 + f2] +
                          part[nn * 256 + 128 + f2] + part[nn * 256 + 192 + f2] + b1[f2];
                float val = fmaxf(s, 0.f);
                h0[(size_t)node * HID + f2] = val;
                hp[(size_t)node * HID + f2] = val * dinv[node];
            }
        }
        __syncthreads();
    }
}

// ---------- fused layer: agg -> blend -> (out@W via LDS broadcast) -> relu ----------
// one wave per node; lane = feature; W column f in 64 VGPRs; per-wave LDS strip
__global__ void gcnii_fused(const float* __restrict__ hp, const float* __restrict__ h0,
                            const float* __restrict__ dinv,
                            const int* __restrict__ row_start, const int* __restrict__ cnt,
                            const int* __restrict__ csr_src,
                            const float* __restrict__ W, float beta, int scale_out,
                            float* __restrict__ hp_next, int n) {
    __shared__ __align__(16) float os[4 * HID];   // 1 KB: one 64-row per wave
    int f = threadIdx.x & 63;
    int wv = threadIdx.x >> 6;
    float* myrow = &os[wv * HID];
    const float4* myrow4 = (const float4*)myrow;
    float wreg[64];
#pragma unroll
    for (int k = 0; k < 64; k++) wreg[k] = W[k * HID + f];
    int wid = blockIdx.x * 4 + wv;
    int nw = gridDim.x * 4;
    for (int v = wid; v < n; v += nw) {
        float acc = hp[(size_t)v * HID + f];   // self loop (hp carries dinv[v])
        int j = row_start[v];
        int end = j + cnt[v];
        for (; j + 8 <= end; j += 8) {
            int s0 = csr_src[j],     s1 = csr_src[j + 1];
            int s2 = csr_src[j + 2], s3 = csr_src[j + 3];
            int s4 = csr_src[j + 4], s5 = csr_src[j + 5];
            int s6 = csr_src[j + 6], s7 = csr_src[j + 7];
            float a0 = hp[(size_t)s0 * HID + f];
            float a1 = hp[(size_t)s1 * HID + f];
            float a2 = hp[(size_t)s2 * HID + f];
            float a3 = hp[(size_t)s3 * HID + f];
            float a4 = hp[(size_t)s4 * HID + f];
            float a5 = hp[(size_t)s5 * HID + f];
            float a6 = hp[(size_t)s6 * HID + f];
            float a7 = hp[(size_t)s7 * HID + f];
            acc += ((a0 + a1) + (a2 + a3)) + ((a4 + a5) + (a6 + a7));
        }
        for (; j < end; ++j) acc += hp[(size_t)csr_src[j] * HID + f];
        float dv = dinv[v];
        float out = 0.9f * dv * acc + 0.1f * h0[(size_t)v * HID + f];
        // dense dot via wave-private LDS strip (no __syncthreads needed)
        myrow[f] = out;
        float dot = 0.f;
#pragma unroll
        for (int q = 0; q < 16; q++) {
            float4 o4 = myrow4[q];             // broadcast ds_read_b128
            dot += o4.x * wreg[4 * q] + o4.y * wreg[4 * q + 1] +
                   o4.z * wreg[4 * q + 2] + o4.w * wreg[4 * q + 3];
        }
        float val = fmaxf((1.f - beta) * out + beta * dot, 0.f);
        hp_next[(size_t)v * HID + f] = scale_out ? dv * val : val;
    }
}

// ---------- y = h @ W2 + b2 ----------
__global__ void mlp_out(const float* __restrict__ h, const float* __restrict__ W2,
                        const float* __restrict__ b2, float* __restrict__ y, int n) {
    __shared__ float hs[32 * HID];
    __shared__ float W2s[HID * DOUT];
    __shared__ float b2s[DOUT];
    int t = threadIdx.x;
    for (int i = t; i < HID * DOUT; i += 256) W2s[i] = W2[i];
    if (t < DOUT) b2s[t] = b2[t];
    int node0 = blockIdx.x * 32;
    for (int i = t; i < 32 * HID; i += 256) {
        int node = node0 + (i >> 6);
        hs[i] = (node < n) ? h[(size_t)node0 * HID + i] : 0.f;
    }
    __syncthreads();
    for (int idx = t; idx < 32 * DOUT; idx += 256) {
        int nloc = idx / DOUT, fo = idx % DOUT;
        int node = node0 + nloc;
        if (node >= n) continue;
        float dot = b2s[fo];
#pragma unroll 8
        for (int k = 0; k < HID; k++) dot += hs[nloc * HID + k] * W2s[k * DOUT + fo];
        y[(size_t)node * DOUT + fo] = dot;
    }
}

extern "C" void kernel_launch(void* const* d_in, const int* in_sizes, int n_in,
                              void* d_out, int out_size, void* d_ws, size_t ws_size,
                              hipStream_t stream) {
    const float*    x     = (const float*)d_in[0];
    const uint32_t* ei    = (const uint32_t*)d_in[1];
    const float*    W1    = (const float*)d_in[2];
    const float*    b1    = (const float*)d_in[3];
    const float*    convw = (const float*)d_in[4];
    const float*    W2    = (const float*)d_in[5];
    const float*    b2    = (const float*)d_in[6];
    float*          y     = (float*)d_out;

    int N = in_sizes[0] / DIN;
    int E = in_sizes[1] / 2;

    char* ws = (char*)d_ws;
    size_t off = 0;
    auto alloc = [&](size_t bytes) -> char* {
        char* p = ws + off;
        off = (off + bytes + 255) & ~(size_t)255;
        return p;
    };
    int*   flag      = (int*)alloc(4);
    int*   cnt       = (int*)alloc((size_t)N * 4);
    int*   row_start = (int*)alloc((size_t)N * 4);
    float* dinv      = (float*)alloc((size_t)N * 4);
    int*   blocksum  = (int*)alloc(512 * 4);
    int*   pw        = (int*)alloc((size_t)E * 4);
    int*   csr_src   = (int*)alloc((size_t)E * 4);
    float* h0        = (float*)alloc((size_t)N * HID * 4);
    float* hpA       = (float*)alloc((size_t)N * HID * 4);
    float* hpB       = (float*)alloc((size_t)N * HID * 4);

    detect_i64<<<1, 64, 0, stream>>>(ei, flag);
    init_cnt<<<cdiv(N, 256), 256, 0, stream>>>(cnt, N);
    count_pos<<<cdiv(E, 256), 256, 0, stream>>>(ei, flag, cnt, pw, E);
    int nb = cdiv(N, 256);
    scan1<<<nb, 256, 0, stream>>>(cnt, row_start, blocksum, N);
    scan2<<<1, 512, 0, stream>>>(blocksum, nb);
    scan3<<<cdiv(N, 256), 256, 0, stream>>>(row_start, blocksum, N);
    compute_dinv<<<cdiv(N, 256), 256, 0, stream>>>(cnt, dinv, N);
    scatter_pos<<<cdiv(E, 256), 256, 0, stream>>>(ei, flag, row_start, pw, csr_src, E);

    mlp_in_v3<<<cdiv(N, MT), 256, 0, stream>>>(x, W1, b1, dinv, hpA, h0, N);

    float* cur = hpA;
    float* nxt = hpB;
    for (int i = 0; i < N_LAYERS; i++) {
        float beta = logf(0.5f / (float)(i + 1) + 1.f);
        int scale_out = (i < N_LAYERS - 1) ? 1 : 0;
        gcnii_fused<<<2048, 256, 0, stream>>>(cur, h0, dinv, row_start, cnt, csr_src,
                                              convw + (size_t)i * HID * HID, beta,
                                              scale_out, nxt, N);
        float* tmp = cur; cur = nxt; nxt = tmp;
    }
    mlp_out<<<cdiv(N, 32), 256, 0, stream>>>(cur, W2, b2, y, N);
}

// Round 5
// 1049.673 us; speedup vs baseline: 2.8560x; 1.3097x over previous
//
#include <hip/hip_runtime.h>
#include <hip/hip_fp16.h>
#include <stdint.h>
#include <math.h>

#define HID 64
#define DIN 128
#define DOUT 40
#define N_LAYERS 8

static inline int cdiv(int a, int b) { return (a + b - 1) / b; }

// ---------- edge-index layout detection (int32 vs int64 storage) ----------
__global__ void detect_i64(const uint32_t* __restrict__ ei, int* __restrict__ flag) {
    int t = threadIdx.x;
    uint32_t w = ei[2 * t + 1];
    unsigned long long nz = __ballot(w != 0u);
    if (t == 0) *flag = (nz == 0ull) ? 1 : 0;
}

__device__ __forceinline__ int edge_src(const uint32_t* ei, int is64, int E, int e) {
    return is64 ? (int)ei[2 * e] : (int)ei[e];
}
__device__ __forceinline__ int edge_dst(const uint32_t* ei, int is64, int E, int e) {
    return is64 ? (int)ei[2 * (size_t)E + 2 * e] : (int)ei[(size_t)E + e];
}

// ---------- CSR construction (split-phase ticket) ----------
__global__ void init_cnt(int* __restrict__ cnt, int n) {
    int v = blockIdx.x * blockDim.x + threadIdx.x;
    if (v < n) cnt[v] = 0;
}

__global__ void count_pos(const uint32_t* __restrict__ ei, const int* __restrict__ flag,
                          int* __restrict__ cnt, int* __restrict__ pw, int E) {
    int e = blockIdx.x * blockDim.x + threadIdx.x;
    if (e >= E) return;
    int is64 = *flag;
    int d = edge_dst(ei, is64, E, e);
    pw[e] = atomicAdd(&cnt[d], 1);
}

__global__ void scan1(const int* __restrict__ cnt, int* __restrict__ row_start,
                      int* __restrict__ blocksum, int n) {
    __shared__ int sh[256];
    int t = threadIdx.x;
    int v = blockIdx.x * 256 + t;
    int val = (v < n) ? cnt[v] : 0;
    sh[t] = val;
    __syncthreads();
    for (int o = 1; o < 256; o <<= 1) {
        int y = (t >= o) ? sh[t - o] : 0;
        __syncthreads();
        sh[t] += y;
        __syncthreads();
    }
    if (v < n) row_start[v] = sh[t] - val;
    if (t == 255) blocksum[blockIdx.x] = sh[255];
}

__global__ void scan2(int* __restrict__ blocksum, int nb) {
    __shared__ int sh[512];
    int t = threadIdx.x;
    int val = (t < nb) ? blocksum[t] : 0;
    sh[t] = val;
    __syncthreads();
    for (int o = 1; o < 512; o <<= 1) {
        int y = (t >= o) ? sh[t - o] : 0;
        __syncthreads();
        sh[t] += y;
        __syncthreads();
    }
    if (t < nb) blocksum[t] = sh[t] - val;
}

__global__ void scan3(int* __restrict__ row_start, const int* __restrict__ blocksum, int n) {
    int v = blockIdx.x * 256 + threadIdx.x;
    if (v < n) row_start[v] += blocksum[v >> 8];
}

__global__ void compute_dinv(const int* __restrict__ cnt, float* __restrict__ dinv, int n) {
    int v = blockIdx.x * blockDim.x + threadIdx.x;
    if (v < n) dinv[v] = rsqrtf((float)(cnt[v] + 1));
}

__global__ void scatter_pos(const uint32_t* __restrict__ ei, const int* __restrict__ flag,
                            const int* __restrict__ row_start, const int* __restrict__ pw,
                            int* __restrict__ csr_src, int E) {
    int e = blockIdx.x * blockDim.x + threadIdx.x;
    if (e >= E) return;
    int is64 = *flag;
    int s = edge_src(ei, is64, E, e);
    int d = edge_dst(ei, is64, E, e);
    csr_src[row_start[d] + pw[e]] = s;
}

// ---------- h0 = relu(x @ W1 + b1) [f32]; hp = fp16(dinv * h0) ----------
#define MT 16
__global__ void mlp_in_v3(const float* __restrict__ x, const float* __restrict__ W1,
                          const float* __restrict__ b1, const float* __restrict__ dinv,
                          __half* __restrict__ hp, float* __restrict__ h0, int n) {
    __shared__ __align__(16) float xs[MT * DIN];
    __shared__ float part[MT * 256];
    int t = threadIdx.x;
    int f = t & 63, wv = t >> 6;
    float wreg[32];
#pragma unroll
    for (int kk = 0; kk < 32; kk++) wreg[kk] = W1[(32 * wv + kk) * HID + f];
    int ntiles = (n + MT - 1) / MT;
    for (int tile = blockIdx.x; tile < ntiles; tile += gridDim.x) {
        int node0 = tile * MT;
        const float4* xsrc = (const float4*)(x + (size_t)node0 * DIN);
        float4* xd = (float4*)xs;
        int lim = (min(MT, n - node0) * DIN) >> 2;
#pragma unroll
        for (int r = 0; r < (MT * DIN / 4) / 256; r++) {
            int i = r * 256 + t;
            xd[i] = (i < lim) ? xsrc[i] : make_float4(0.f, 0.f, 0.f, 0.f);
        }
        __syncthreads();
        const float4* xs4 = (const float4*)xs;
#pragma unroll
        for (int nn = 0; nn < MT; nn++) {
            float partial = 0.f;
#pragma unroll
            for (int q = 0; q < 8; q++) {
                float4 xv = xs4[nn * (DIN / 4) + wv * 8 + q];
                partial += xv.x * wreg[4 * q] + xv.y * wreg[4 * q + 1] +
                           xv.z * wreg[4 * q + 2] + xv.w * wreg[4 * q + 3];
            }
            part[nn * 256 + wv * 64 + f] = partial;
        }
        __syncthreads();
#pragma unroll
        for (int r = 0; r < (MT * 64) / 256; r++) {
            int idx = r * 256 + t;
            int nn = idx >> 6, f2 = idx & 63;
            int node = node0 + nn;
            if (node < n) {
                float s = part[nn * 256 + f2] + part[nn * 256 + 64 + f2] +
                          part[nn * 256 + 128 + f2] + part[nn * 256 + 192 + f2] + b1[f2];
                float val = fmaxf(s, 0.f);
                h0[(size_t)node * HID + f2] = val;
                hp[(size_t)node * HID + f2] = __float2half(val * dinv[node]);
            }
        }
        __syncthreads();
    }
}

// ---------- SpMM (fp16 gathers): out = 0.9*dv*(self+agg) + 0.1*h0 [f32] ----------
// one wave per node; lane = feature
__global__ void spmm_h(const __half* __restrict__ hp, const float* __restrict__ h0,
                       const float* __restrict__ dinv,
                       const int* __restrict__ row_start, const int* __restrict__ cnt,
                       const int* __restrict__ csr_src,
                       float* __restrict__ out, int n) {
    int v = (blockIdx.x * blockDim.x + threadIdx.x) >> 6;
    int lane = threadIdx.x & 63;
    if (v >= n) return;
    float acc = __half2float(hp[(size_t)v * HID + lane]);   // self loop (hp carries dinv[v])
    int j = row_start[v];
    int end = j + cnt[v];
    for (; j + 8 <= end; j += 8) {
        int s0 = csr_src[j],     s1 = csr_src[j + 1];
        int s2 = csr_src[j + 2], s3 = csr_src[j + 3];
        int s4 = csr_src[j + 4], s5 = csr_src[j + 5];
        int s6 = csr_src[j + 6], s7 = csr_src[j + 7];
        float a0 = __half2float(hp[(size_t)s0 * HID + lane]);
        float a1 = __half2float(hp[(size_t)s1 * HID + lane]);
        float a2 = __half2float(hp[(size_t)s2 * HID + lane]);
        float a3 = __half2float(hp[(size_t)s3 * HID + lane]);
        float a4 = __half2float(hp[(size_t)s4 * HID + lane]);
        float a5 = __half2float(hp[(size_t)s5 * HID + lane]);
        float a6 = __half2float(hp[(size_t)s6 * HID + lane]);
        float a7 = __half2float(hp[(size_t)s7 * HID + lane]);
        acc += ((a0 + a1) + (a2 + a3)) + ((a4 + a5) + (a6 + a7));
    }
    for (; j < end; ++j) acc += __half2float(hp[(size_t)csr_src[j] * HID + lane]);
    float dv = dinv[v];
    out[(size_t)v * HID + lane] = 0.9f * dv * acc + 0.1f * h0[(size_t)v * HID + lane];
}

// ---------- dense: hp_next = fp16((dinv*)? relu((1-beta)*out + beta*(out @ W))) ----
__global__ void layer_mlp(const float* __restrict__ out, const float* __restrict__ W,
                          const float* __restrict__ dinv, float beta, int scale_out,
                          __half* __restrict__ hpn, int n) {
    __shared__ __align__(16) float os[32 * HID];
    int t = threadIdx.x;
    int f = t & 63, wv = t >> 6;
    float wc[64];
#pragma unroll
    for (int k = 0; k < 64; k++) wc[k] = W[k * HID + f];
    int ntiles = (n + 31) / 32;
    for (int tile = blockIdx.x; tile < ntiles; tile += gridDim.x) {
        int node0 = tile * 32;
        for (int i = t; i < 32 * HID; i += 256) {
            int node = node0 + (i >> 6);
            os[i] = (node < n) ? out[(size_t)node0 * HID + i] : 0.f;
        }
        __syncthreads();
        const float4* os4 = (const float4*)os;
#pragma unroll
        for (int k = 0; k < 8; k++) {
            int nloc = wv + 4 * k;
            int node = node0 + nloc;
            if (node < n) {
                float dot = 0.f;
#pragma unroll
                for (int q = 0; q < 16; q++) {
                    float4 o4 = os4[nloc * 16 + q];
                    dot += o4.x * wc[4 * q] + o4.y * wc[4 * q + 1] +
                           o4.z * wc[4 * q + 2] + o4.w * wc[4 * q + 3];
                }
                float o = os[nloc * HID + f];
                float val = fmaxf((1.f - beta) * o + beta * dot, 0.f);
                if (scale_out) val *= dinv[node];
                hpn[(size_t)node * HID + f] = __float2half(val);
            }
        }
        __syncthreads();
    }
}

// ---------- y = h @ W2 + b2  (h fp16) ----------
__global__ void mlp_out(const __half* __restrict__ h, const float* __restrict__ W2,
                        const float* __restrict__ b2, float* __restrict__ y, int n) {
    __shared__ float hs[32 * HID];
    __shared__ float W2s[HID * DOUT];
    __shared__ float b2s[DOUT];
    int t = threadIdx.x;
    for (int i = t; i < HID * DOUT; i += 256) W2s[i] = W2[i];
    if (t < DOUT) b2s[t] = b2[t];
    int node0 = blockIdx.x * 32;
    for (int i = t; i < 32 * HID; i += 256) {
        int node = node0 + (i >> 6);
        hs[i] = (node < n) ? __half2float(h[(size_t)node0 * HID + i]) : 0.f;
    }
    __syncthreads();
    for (int idx = t; idx < 32 * DOUT; idx += 256) {
        int nloc = idx / DOUT, fo = idx % DOUT;
        int node = node0 + nloc;
        if (node >= n) continue;
        float dot = b2s[fo];
#pragma unroll 8
        for (int k = 0; k < HID; k++) dot += hs[nloc * HID + k] * W2s[k * DOUT + fo];
        y[(size_t)node * DOUT + fo] = dot;
    }
}

extern "C" void kernel_launch(void* const* d_in, const int* in_sizes, int n_in,
                              void* d_out, int out_size, void* d_ws, size_t ws_size,
                              hipStream_t stream) {
    const float*    x     = (const float*)d_in[0];
    const uint32_t* ei    = (const uint32_t*)d_in[1];
    const float*    W1    = (const float*)d_in[2];
    const float*    b1    = (const float*)d_in[3];
    const float*    convw = (const float*)d_in[4];
    const float*    W2    = (const float*)d_in[5];
    const float*    b2    = (const float*)d_in[6];
    float*          y     = (float*)d_out;

    int N = in_sizes[0] / DIN;
    int E = in_sizes[1] / 2;

    char* ws = (char*)d_ws;
    size_t off = 0;
    auto alloc = [&](size_t bytes) -> char* {
        char* p = ws + off;
        off = (off + bytes + 255) & ~(size_t)255;
        return p;
    };
    int*    flag      = (int*)alloc(4);
    int*    cnt       = (int*)alloc((size_t)N * 4);
    int*    row_start = (int*)alloc((size_t)N * 4);
    float*  dinv      = (float*)alloc((size_t)N * 4);
    int*    blocksum  = (int*)alloc(512 * 4);
    int*    pw        = (int*)alloc((size_t)E * 4);
    int*    csr_src   = (int*)alloc((size_t)E * 4);
    float*  h0        = (float*)alloc((size_t)N * HID * 4);
    float*  outb      = (float*)alloc((size_t)N * HID * 4);
    __half* hpA       = (__half*)alloc((size_t)N * HID * 2);
    __half* hpB       = (__half*)alloc((size_t)N * HID * 2);

    detect_i64<<<1, 64, 0, stream>>>(ei, flag);
    init_cnt<<<cdiv(N, 256), 256, 0, stream>>>(cnt, N);
    count_pos<<<cdiv(E, 256), 256, 0, stream>>>(ei, flag, cnt, pw, E);
    int nb = cdiv(N, 256);
    scan1<<<nb, 256, 0, stream>>>(cnt, row_start, blocksum, N);
    scan2<<<1, 512, 0, stream>>>(blocksum, nb);
    scan3<<<cdiv(N, 256), 256, 0, stream>>>(row_start, blocksum, N);
    compute_dinv<<<cdiv(N, 256), 256, 0, stream>>>(cnt, dinv, N);
    scatter_pos<<<cdiv(E, 256), 256, 0, stream>>>(ei, flag, row_start, pw, csr_src, E);

    mlp_in_v3<<<cdiv(N, MT), 256, 0, stream>>>(x, W1, b1, dinv, hpA, h0, N);

    __half* cur = hpA;
    __half* nxt = hpB;
    for (int i = 0; i < N_LAYERS; i++) {
        float beta = logf(0.5f / (float)(i + 1) + 1.f);
        int scale_out = (i < N_LAYERS - 1) ? 1 : 0;
        spmm_h<<<cdiv(N, 4), 256, 0, stream>>>(cur, h0, dinv, row_start, cnt, csr_src,
                                               outb, N);
        layer_mlp<<<2048, 256, 0, stream>>>(outb, convw + (size_t)i * HID * HID,
                                            dinv, beta, scale_out, nxt, N);
        __half* tmp = cur; cur = nxt; nxt = tmp;
    }
    mlp_out<<<cdiv(N, 32), 256, 0, stream>>>(cur, W2, b2, y, N);
}

// Round 6
// 982.290 us; speedup vs baseline: 3.0519x; 1.0686x over previous
//
#include <hip/hip_runtime.h>
#include <hip/hip_fp16.h>
#include <stdint.h>
#include <math.h>

#define HID 64
#define DIN 128
#define DOUT 40
#define N_LAYERS 8

static inline int cdiv(int a, int b) { return (a + b - 1) / b; }

// ---------- edge-index layout detection (int32 vs int64 storage) ----------
__global__ void detect_i64(const uint32_t* __restrict__ ei, int* __restrict__ flag) {
    int t = threadIdx.x;
    uint32_t w = ei[2 * t + 1];
    unsigned long long nz = __ballot(w != 0u);
    if (t == 0) *flag = (nz == 0ull) ? 1 : 0;
}

__device__ __forceinline__ int edge_src(const uint32_t* ei, int is64, int E, int e) {
    return is64 ? (int)ei[2 * e] : (int)ei[e];
}
__device__ __forceinline__ int edge_dst(const uint32_t* ei, int is64, int E, int e) {
    return is64 ? (int)ei[2 * (size_t)E + 2 * e] : (int)ei[(size_t)E + e];
}

// ---------- CSR construction (split-phase ticket) ----------
__global__ void init_cnt(int* __restrict__ cnt, int n) {
    int v = blockIdx.x * blockDim.x + threadIdx.x;
    if (v < n) cnt[v] = 0;
}

__global__ void count_pos(const uint32_t* __restrict__ ei, const int* __restrict__ flag,
                          int* __restrict__ cnt, int* __restrict__ pw, int E) {
    int e = blockIdx.x * blockDim.x + threadIdx.x;
    if (e >= E) return;
    int is64 = *flag;
    int d = edge_dst(ei, is64, E, e);
    pw[e] = atomicAdd(&cnt[d], 1);
}

__global__ void scan1(const int* __restrict__ cnt, int* __restrict__ row_start,
                      int* __restrict__ blocksum, int n) {
    __shared__ int sh[256];
    int t = threadIdx.x;
    int v = blockIdx.x * 256 + t;
    int val = (v < n) ? cnt[v] : 0;
    sh[t] = val;
    __syncthreads();
    for (int o = 1; o < 256; o <<= 1) {
        int y = (t >= o) ? sh[t - o] : 0;
        __syncthreads();
        sh[t] += y;
        __syncthreads();
    }
    if (v < n) row_start[v] = sh[t] - val;
    if (t == 255) blocksum[blockIdx.x] = sh[255];
}

__global__ void scan2(int* __restrict__ blocksum, int nb) {
    __shared__ int sh[512];
    int t = threadIdx.x;
    int val = (t < nb) ? blocksum[t] : 0;
    sh[t] = val;
    __syncthreads();
    for (int o = 1; o < 512; o <<= 1) {
        int y = (t >= o) ? sh[t - o] : 0;
        __syncthreads();
        sh[t] += y;
        __syncthreads();
    }
    if (t < nb) blocksum[t] = sh[t] - val;
}

__global__ void scan3(int* __restrict__ row_start, const int* __restrict__ blocksum, int n) {
    int v = blockIdx.x * 256 + threadIdx.x;
    if (v < n) row_start[v] += blocksum[v >> 8];
}

__global__ void compute_dinv(const int* __restrict__ cnt, float* __restrict__ dinv, int n) {
    int v = blockIdx.x * blockDim.x + threadIdx.x;
    if (v < n) dinv[v] = rsqrtf((float)(cnt[v] + 1));
}

__global__ void scatter_pos(const uint32_t* __restrict__ ei, const int* __restrict__ flag,
                            const int* __restrict__ row_start, const int* __restrict__ pw,
                            int* __restrict__ csr_src, int E) {
    int e = blockIdx.x * blockDim.x + threadIdx.x;
    if (e >= E) return;
    int is64 = *flag;
    int s = edge_src(ei, is64, E, e);
    int d = edge_dst(ei, is64, E, e);
    csr_src[row_start[d] + pw[e]] = s;
}

// ---------- h0 = relu(x @ W1 + b1) [f32]; hp = fp16(dinv * h0) ----------
#define MT 16
__global__ void mlp_in_v3(const float* __restrict__ x, const float* __restrict__ W1,
                          const float* __restrict__ b1, const float* __restrict__ dinv,
                          __half* __restrict__ hp, float* __restrict__ h0, int n) {
    __shared__ __align__(16) float xs[MT * DIN];
    __shared__ float part[MT * 256];
    int t = threadIdx.x;
    int f = t & 63, wv = t >> 6;
    float wreg[32];
#pragma unroll
    for (int kk = 0; kk < 32; kk++) wreg[kk] = W1[(32 * wv + kk) * HID + f];
    int ntiles = (n + MT - 1) / MT;
    for (int tile = blockIdx.x; tile < ntiles; tile += gridDim.x) {
        int node0 = tile * MT;
        const float4* xsrc = (const float4*)(x + (size_t)node0 * DIN);
        float4* xd = (float4*)xs;
        int lim = (min(MT, n - node0) * DIN) >> 2;
#pragma unroll
        for (int r = 0; r < (MT * DIN / 4) / 256; r++) {
            int i = r * 256 + t;
            xd[i] = (i < lim) ? xsrc[i] : make_float4(0.f, 0.f, 0.f, 0.f);
        }
        __syncthreads();
        const float4* xs4 = (const float4*)xs;
#pragma unroll
        for (int nn = 0; nn < MT; nn++) {
            float partial = 0.f;
#pragma unroll
            for (int q = 0; q < 8; q++) {
                float4 xv = xs4[nn * (DIN / 4) + wv * 8 + q];
                partial += xv.x * wreg[4 * q] + xv.y * wreg[4 * q + 1] +
                           xv.z * wreg[4 * q + 2] + xv.w * wreg[4 * q + 3];
            }
            part[nn * 256 + wv * 64 + f] = partial;
        }
        __syncthreads();
#pragma unroll
        for (int r = 0; r < (MT * 64) / 256; r++) {
            int idx = r * 256 + t;
            int nn = idx >> 6, f2 = idx & 63;
            int node = node0 + nn;
            if (node < n) {
                float s = part[nn * 256 + f2] + part[nn * 256 + 64 + f2] +
                          part[nn * 256 + 128 + f2] + part[nn * 256 + 192 + f2] + b1[f2];
                float val = fmaxf(s, 0.f);
                h0[(size_t)node * HID + f2] = val;
                hp[(size_t)node * HID + f2] = __float2half(val * dinv[node]);
            }
        }
        __syncthreads();
    }
}

// ---------- SpMM half2: agg' = 0.9*dv*(self + sum_src hp) stored fp16 ----------
// one wave per node; lane = (f2 = lane&31 feature-pair) x (g = lane>>5 edge group)
__global__ void spmm_h2(const __half2* __restrict__ hp2,
                        const int* __restrict__ row_start, const int* __restrict__ cnt,
                        const int* __restrict__ csr_src, const float* __restrict__ dinv,
                        __half2* __restrict__ agg, int n) {
    int v = (blockIdx.x * blockDim.x + threadIdx.x) >> 6;
    int lane = threadIdx.x & 63;
    if (v >= n) return;
    int f2 = lane & 31, g = lane >> 5;
    float ax = 0.f, ay = 0.f;
    if (g == 0) {   // self loop term
        __half2 s = hp2[(size_t)v * 32 + f2];
        ax = __half2float(s.x); ay = __half2float(s.y);
    }
    int j = row_start[v];
    int end = j + cnt[v];
    int e = j + g;   // group g walks edges j+g, j+g+2, ...
    for (; e + 6 < end; e += 8) {
        int s0 = csr_src[e],     s1 = csr_src[e + 2];
        int s2 = csr_src[e + 4], s3 = csr_src[e + 6];
        __half2 a0 = hp2[(size_t)s0 * 32 + f2];
        __half2 a1 = hp2[(size_t)s1 * 32 + f2];
        __half2 a2 = hp2[(size_t)s2 * 32 + f2];
        __half2 a3 = hp2[(size_t)s3 * 32 + f2];
        float2 f0 = __half22float2(a0), f1 = __half22float2(a1);
        float2 f2v = __half22float2(a2), f3 = __half22float2(a3);
        ax += (f0.x + f1.x) + (f2v.x + f3.x);
        ay += (f0.y + f1.y) + (f2v.y + f3.y);
    }
    for (; e < end; e += 2) {
        float2 fv = __half22float2(hp2[(size_t)csr_src[e] * 32 + f2]);
        ax += fv.x; ay += fv.y;
    }
    ax += __shfl_xor(ax, 32);
    ay += __shfl_xor(ay, 32);
    if (g == 0) {
        float s = 0.9f * dinv[v];
        agg[(size_t)v * 32 + f2] = __floats2half2_rn(s * ax, s * ay);
    }
}

// ---------- dense: out = agg' + 0.1*h0 ; hpn = fp16((dinv*)? relu((1-b)out + b out@W))
__global__ void layer_mlp(const __half2* __restrict__ agg, const float* __restrict__ h0,
                          const float* __restrict__ W, const float* __restrict__ dinv,
                          float beta, int scale_out, __half* __restrict__ hpn, int n) {
    __shared__ __align__(16) float os[32 * HID];
    int t = threadIdx.x;
    int f = t & 63, wv = t >> 6;
    float wc[64];
#pragma unroll
    for (int k = 0; k < 64; k++) wc[k] = W[k * HID + f];
    const float2* h02 = (const float2*)h0;
    int ntiles = (n + 31) / 32;
    for (int tile = blockIdx.x; tile < ntiles; tile += gridDim.x) {
        int node0 = tile * 32;
        // stage out = agg' + 0.1*h0 into LDS (f32)
#pragma unroll
        for (int r = 0; r < 4; r++) {
            int i = r * 256 + t;          // i in [0,1024): node = i>>5, feat-pair = i&31
            int node = node0 + (i >> 5);
            float2 val = make_float2(0.f, 0.f);
            if (node < n) {
                float2 a = __half22float2(agg[(size_t)node0 * 32 + i]);
                float2 h = h02[(size_t)node0 * 32 + i];
                val.x = a.x + 0.1f * h.x;
                val.y = a.y + 0.1f * h.y;
            }
            int nloc = i >> 5, fp = i & 31;
            os[nloc * HID + 2 * fp]     = val.x;   // 2-way stride: free tier
            os[nloc * HID + 2 * fp + 1] = val.y;
        }
        __syncthreads();
        const float4* os4 = (const float4*)os;
#pragma unroll
        for (int k = 0; k < 8; k++) {
            int nloc = wv + 4 * k;
            int node = node0 + nloc;
            if (node < n) {
                float dot = 0.f;
#pragma unroll
                for (int q = 0; q < 16; q++) {
                    float4 o4 = os4[nloc * 16 + q];
                    dot += o4.x * wc[4 * q] + o4.y * wc[4 * q + 1] +
                           o4.z * wc[4 * q + 2] + o4.w * wc[4 * q + 3];
                }
                float o = os[nloc * HID + f];
                float val = fmaxf((1.f - beta) * o + beta * dot, 0.f);
                if (scale_out) val *= dinv[node];
                hpn[(size_t)node * HID + f] = __float2half(val);
            }
        }
        __syncthreads();
    }
}

// ---------- y = h @ W2 + b2  (h fp16) ----------
__global__ void mlp_out(const __half* __restrict__ h, const float* __restrict__ W2,
                        const float* __restrict__ b2, float* __restrict__ y, int n) {
    __shared__ float hs[32 * HID];
    __shared__ float W2s[HID * DOUT];
    __shared__ float b2s[DOUT];
    int t = threadIdx.x;
    for (int i = t; i < HID * DOUT; i += 256) W2s[i] = W2[i];
    if (t < DOUT) b2s[t] = b2[t];
    int node0 = blockIdx.x * 32;
    for (int i = t; i < 32 * HID; i += 256) {
        int node = node0 + (i >> 6);
        hs[i] = (node < n) ? __half2float(h[(size_t)node0 * HID + i]) : 0.f;
    }
    __syncthreads();
    for (int idx = t; idx < 32 * DOUT; idx += 256) {
        int nloc = idx / DOUT, fo = idx % DOUT;
        int node = node0 + nloc;
        if (node >= n) continue;
        float dot = b2s[fo];
#pragma unroll 8
        for (int k = 0; k < HID; k++) dot += hs[nloc * HID + k] * W2s[k * DOUT + fo];
        y[(size_t)node * DOUT + fo] = dot;
    }
}

extern "C" void kernel_launch(void* const* d_in, const int* in_sizes, int n_in,
                              void* d_out, int out_size, void* d_ws, size_t ws_size,
                              hipStream_t stream) {
    const float*    x     = (const float*)d_in[0];
    const uint32_t* ei    = (const uint32_t*)d_in[1];
    const float*    W1    = (const float*)d_in[2];
    const float*    b1    = (const float*)d_in[3];
    const float*    convw = (const float*)d_in[4];
    const float*    W2    = (const float*)d_in[5];
    const float*    b2    = (const float*)d_in[6];
    float*          y     = (float*)d_out;

    int N = in_sizes[0] / DIN;
    int E = in_sizes[1] / 2;

    char* ws = (char*)d_ws;
    size_t off = 0;
    auto alloc = [&](size_t bytes) -> char* {
        char* p = ws + off;
        off = (off + bytes + 255) & ~(size_t)255;
        return p;
    };
    int*     flag      = (int*)alloc(4);
    int*     cnt       = (int*)alloc((size_t)N * 4);
    int*     row_start = (int*)alloc((size_t)N * 4);
    float*   dinv      = (float*)alloc((size_t)N * 4);
    int*     blocksum  = (int*)alloc(512 * 4);
    int*     pw        = (int*)alloc((size_t)E * 4);
    int*     csr_src   = (int*)alloc((size_t)E * 4);
    float*   h0        = (float*)alloc((size_t)N * HID * 4);
    __half2* aggb      = (__half2*)alloc((size_t)N * HID * 2);
    __half*  hpA       = (__half*)alloc((size_t)N * HID * 2);
    __half*  hpB       = (__half*)alloc((size_t)N * HID * 2);

    detect_i64<<<1, 64, 0, stream>>>(ei, flag);
    init_cnt<<<cdiv(N, 256), 256, 0, stream>>>(cnt, N);
    count_pos<<<cdiv(E, 256), 256, 0, stream>>>(ei, flag, cnt, pw, E);
    int nb = cdiv(N, 256);
    scan1<<<nb, 256, 0, stream>>>(cnt, row_start, blocksum, N);
    scan2<<<1, 512, 0, stream>>>(blocksum, nb);
    scan3<<<cdiv(N, 256), 256, 0, stream>>>(row_start, blocksum, N);
    compute_dinv<<<cdiv(N, 256), 256, 0, stream>>>(cnt, dinv, N);
    scatter_pos<<<cdiv(E, 256), 256, 0, stream>>>(ei, flag, row_start, pw, csr_src, E);

    mlp_in_v3<<<cdiv(N, MT), 256, 0, stream>>>(x, W1, b1, dinv, hpA, h0, N);

    __half* cur = hpA;
    __half* nxt = hpB;
    for (int i = 0; i < N_LAYERS; i++) {
        float beta = logf(0.5f / (float)(i + 1) + 1.f);
        int scale_out = (i < N_LAYERS - 1) ? 1 : 0;
        spmm_h2<<<cdiv(N, 4), 256, 0, stream>>>((const __half2*)cur, row_start, cnt,
                                                csr_src, dinv, aggb, N);
        layer_mlp<<<2048, 256, 0, stream>>>(aggb, h0, convw + (size_t)i * HID * HID,
                                            dinv, beta, scale_out, nxt, N);
        cur = (cur == hpA) ? hpB : hpA;
        nxt = (nxt == hpA) ? hpB : hpA;
    }
    mlp_out<<<cdiv(N, 32), 256, 0, stream>>>(cur, W2, b2, y, N);
}

// Round 7
// 875.564 us; speedup vs baseline: 3.4239x; 1.1219x over previous
//
#include <hip/hip_runtime.h>
#include <hip/hip_fp16.h>
#include <stdint.h>
#include <math.h>

#define HID 64
#define DIN 128
#define DOUT 40
#define N_LAYERS 8

typedef _Float16 half8 __attribute__((ext_vector_type(8)));
typedef float f32x4 __attribute__((ext_vector_type(4)));

static inline int cdiv(int a, int b) { return (a + b - 1) / b; }

// ---------- edge-index layout detection (int32 vs int64 storage) ----------
__global__ void detect_i64(const uint32_t* __restrict__ ei, int* __restrict__ flag) {
    int t = threadIdx.x;
    uint32_t w = ei[2 * t + 1];
    unsigned long long nz = __ballot(w != 0u);
    if (t == 0) *flag = (nz == 0ull) ? 1 : 0;
}

__device__ __forceinline__ int edge_src(const uint32_t* ei, int is64, int E, int e) {
    return is64 ? (int)ei[2 * e] : (int)ei[e];
}
__device__ __forceinline__ int edge_dst(const uint32_t* ei, int is64, int E, int e) {
    return is64 ? (int)ei[2 * (size_t)E + 2 * e] : (int)ei[(size_t)E + e];
}

// ---------- CSR construction (split-phase ticket) ----------
__global__ void init_cnt(int* __restrict__ cnt, int n) {
    int v = blockIdx.x * blockDim.x + threadIdx.x;
    if (v < n) cnt[v] = 0;
}

__global__ void count_pos(const uint32_t* __restrict__ ei, const int* __restrict__ flag,
                          int* __restrict__ cnt, int* __restrict__ pw, int E) {
    int e = blockIdx.x * blockDim.x + threadIdx.x;
    if (e >= E) return;
    int is64 = *flag;
    int d = edge_dst(ei, is64, E, e);
    pw[e] = atomicAdd(&cnt[d], 1);
}

__global__ void scan1(const int* __restrict__ cnt, int* __restrict__ row_start,
                      int* __restrict__ blocksum, int n) {
    __shared__ int sh[256];
    int t = threadIdx.x;
    int v = blockIdx.x * 256 + t;
    int val = (v < n) ? cnt[v] : 0;
    sh[t] = val;
    __syncthreads();
    for (int o = 1; o < 256; o <<= 1) {
        int y = (t >= o) ? sh[t - o] : 0;
        __syncthreads();
        sh[t] += y;
        __syncthreads();
    }
    if (v < n) row_start[v] = sh[t] - val;
    if (t == 255) blocksum[blockIdx.x] = sh[255];
}

__global__ void scan2(int* __restrict__ blocksum, int nb) {
    __shared__ int sh[512];
    int t = threadIdx.x;
    int val = (t < nb) ? blocksum[t] : 0;
    sh[t] = val;
    __syncthreads();
    for (int o = 1; o < 512; o <<= 1) {
        int y = (t >= o) ? sh[t - o] : 0;
        __syncthreads();
        sh[t] += y;
        __syncthreads();
    }
    if (t < nb) blocksum[t] = sh[t] - val;
}

__global__ void scan3(int* __restrict__ row_start, const int* __restrict__ blocksum, int n) {
    int v = blockIdx.x * 256 + threadIdx.x;
    if (v < n) row_start[v] += blocksum[v >> 8];
}

__global__ void compute_dinv(const int* __restrict__ cnt, float* __restrict__ dinv, int n) {
    int v = blockIdx.x * blockDim.x + threadIdx.x;
    if (v < n) dinv[v] = rsqrtf((float)(cnt[v] + 1));
}

__global__ void scatter_pos(const uint32_t* __restrict__ ei, const int* __restrict__ flag,
                            const int* __restrict__ row_start, const int* __restrict__ pw,
                            int* __restrict__ csr_src, int E) {
    int e = blockIdx.x * blockDim.x + threadIdx.x;
    if (e >= E) return;
    int is64 = *flag;
    int s = edge_src(ei, is64, E, e);
    int d = edge_dst(ei, is64, E, e);
    csr_src[row_start[d] + pw[e]] = s;
}

// ---------- Bp_i = fp16(beta_i * W_i + (1-beta_i) * I), stored transposed [n][k] ----
__global__ void make_bp(const float* __restrict__ convw, __half* __restrict__ Bp) {
    int i = blockIdx.x;
    float beta = logf(0.5f / (float)(i + 1) + 1.f);
    const float* W = convw + (size_t)i * HID * HID;
    __half* out = Bp + (size_t)i * HID * HID;
    for (int idx = threadIdx.x; idx < HID * HID; idx += blockDim.x) {
        int k = idx >> 6, nn = idx & 63;
        float v = beta * W[k * HID + nn] + ((k == nn) ? (1.f - beta) : 0.f);
        out[nn * HID + k] = __float2half(v);
    }
}

// ---------- h0h = fp16(relu(x @ W1 + b1)); hp = fp16(dinv * relu(...)) ----------
#define MT 16
__global__ void mlp_in_v3(const float* __restrict__ x, const float* __restrict__ W1,
                          const float* __restrict__ b1, const float* __restrict__ dinv,
                          __half* __restrict__ hp, __half* __restrict__ h0h, int n) {
    __shared__ __align__(16) float xs[MT * DIN];
    __shared__ float part[MT * 256];
    int t = threadIdx.x;
    int f = t & 63, wv = t >> 6;
    float wreg[32];
#pragma unroll
    for (int kk = 0; kk < 32; kk++) wreg[kk] = W1[(32 * wv + kk) * HID + f];
    int ntiles = (n + MT - 1) / MT;
    for (int tile = blockIdx.x; tile < ntiles; tile += gridDim.x) {
        int node0 = tile * MT;
        const float4* xsrc = (const float4*)(x + (size_t)node0 * DIN);
        float4* xd = (float4*)xs;
        int lim = (min(MT, n - node0) * DIN) >> 2;
#pragma unroll
        for (int r = 0; r < (MT * DIN / 4) / 256; r++) {
            int i = r * 256 + t;
            xd[i] = (i < lim) ? xsrc[i] : make_float4(0.f, 0.f, 0.f, 0.f);
        }
        __syncthreads();
        const float4* xs4 = (const float4*)xs;
#pragma unroll
        for (int nn = 0; nn < MT; nn++) {
            float partial = 0.f;
#pragma unroll
            for (int q = 0; q < 8; q++) {
                float4 xv = xs4[nn * (DIN / 4) + wv * 8 + q];
                partial += xv.x * wreg[4 * q] + xv.y * wreg[4 * q + 1] +
                           xv.z * wreg[4 * q + 2] + xv.w * wreg[4 * q + 3];
            }
            part[nn * 256 + wv * 64 + f] = partial;
        }
        __syncthreads();
#pragma unroll
        for (int r = 0; r < (MT * 64) / 256; r++) {
            int idx = r * 256 + t;
            int nn = idx >> 6, f2 = idx & 63;
            int node = node0 + nn;
            if (node < n) {
                float s = part[nn * 256 + f2] + part[nn * 256 + 64 + f2] +
                          part[nn * 256 + 128 + f2] + part[nn * 256 + 192 + f2] + b1[f2];
                float val = fmaxf(s, 0.f);
                h0h[(size_t)node * HID + f2] = __float2half(val);
                hp[(size_t)node * HID + f2] = __float2half(val * dinv[node]);
            }
        }
        __syncthreads();
    }
}

// ---------- SpMM half2: agg' = 0.9*dv*(self + sum_src hp) stored fp16 ----------
__global__ void spmm_h2(const __half2* __restrict__ hp2,
                        const int* __restrict__ row_start, const int* __restrict__ cnt,
                        const int* __restrict__ csr_src, const float* __restrict__ dinv,
                        __half2* __restrict__ agg, int n) {
    int v = (blockIdx.x * blockDim.x + threadIdx.x) >> 6;
    int lane = threadIdx.x & 63;
    if (v >= n) return;
    int f2 = lane & 31, g = lane >> 5;
    float ax = 0.f, ay = 0.f;
    if (g == 0) {
        __half2 s = hp2[(size_t)v * 32 + f2];
        ax = __half2float(s.x); ay = __half2float(s.y);
    }
    int j = row_start[v];
    int end = j + cnt[v];
    int e = j + g;
    for (; e + 6 < end; e += 8) {
        int s0 = csr_src[e],     s1 = csr_src[e + 2];
        int s2 = csr_src[e + 4], s3 = csr_src[e + 6];
        __half2 a0 = hp2[(size_t)s0 * 32 + f2];
        __half2 a1 = hp2[(size_t)s1 * 32 + f2];
        __half2 a2 = hp2[(size_t)s2 * 32 + f2];
        __half2 a3 = hp2[(size_t)s3 * 32 + f2];
        float2 f0 = __half22float2(a0), f1 = __half22float2(a1);
        float2 f2v = __half22float2(a2), f3 = __half22float2(a3);
        ax += (f0.x + f1.x) + (f2v.x + f3.x);
        ay += (f0.y + f1.y) + (f2v.y + f3.y);
    }
    for (; e < end; e += 2) {
        float2 fv = __half22float2(hp2[(size_t)csr_src[e] * 32 + f2]);
        ax += fv.x; ay += fv.y;
    }
    ax += __shfl_xor(ax, 32);
    ay += __shfl_xor(ay, 32);
    if (g == 0) {
        float s = 0.9f * dinv[v];
        agg[(size_t)v * 32 + f2] = __floats2half2_rn(s * ax, s * ay);
    }
}

// ---------- MFMA dense layer: hpn = fp16((dinv?)*relu((agg + 0.1*h0) @ Bp)) ----------
// 128-node tile/block; 4 waves, each an M=32 strip; Bp = beta*W + (1-beta)*I fp16 [n][k]
__global__ void __launch_bounds__(256) layer_mfma(
        const __half2* __restrict__ agg, const __half2* __restrict__ h0h,
        const __half* __restrict__ Bp, const float* __restrict__ dinv,
        int scale_out, __half2* __restrict__ hpn, int n) {
    __shared__ __align__(16) ushort Bs[64 * 72];    // [n][k] padded (+8 halves)
    __shared__ __align__(16) ushort As[128 * 72];   // [node][k] padded; reused for output
    int t = threadIdx.x;
    // stage Bp -> Bs
    {
        const __half2* B2 = (const __half2*)Bp;
        for (int i = t; i < 64 * 32; i += 256) {
            int bn = i >> 5, kp = i & 31;
            *(__half2*)&Bs[bn * 72 + 2 * kp] = B2[bn * 32 + kp];
        }
    }
    int node0 = blockIdx.x * 128;
    // stage A = fp16(agg + 0.1*h0)
    for (int i = t; i < 128 * 32; i += 256) {
        int nd = i >> 5, kp = i & 31;
        int node = node0 + nd;
        __half2 o;
        if (node < n) {
            float2 a = __half22float2(agg[(size_t)node * 32 + kp]);
            float2 h = __half22float2(h0h[(size_t)node * 32 + kp]);
            o = __floats2half2_rn(a.x + 0.1f * h.x, a.y + 0.1f * h.y);
        } else {
            o = __floats2half2_rn(0.f, 0.f);
        }
        *(__half2*)&As[nd * 72 + 2 * kp] = o;
    }
    __syncthreads();
    int lane = t & 63, wv = t >> 6;
    int nl = lane & 15, quad = lane >> 4;
    int m_base = wv * 32;
    f32x4 C[2][4];
#pragma unroll
    for (int mt = 0; mt < 2; mt++)
#pragma unroll
        for (int nt = 0; nt < 4; nt++) C[mt][nt] = (f32x4)0.f;
#pragma unroll
    for (int kc = 0; kc < 2; kc++) {
        half8 a[2], b[4];
#pragma unroll
        for (int mt = 0; mt < 2; mt++)
            a[mt] = *(const half8*)&As[(m_base + mt * 16 + nl) * 72 + kc * 32 + quad * 8];
#pragma unroll
        for (int nt = 0; nt < 4; nt++)
            b[nt] = *(const half8*)&Bs[(nt * 16 + nl) * 72 + kc * 32 + quad * 8];
#pragma unroll
        for (int mt = 0; mt < 2; mt++)
#pragma unroll
            for (int nt = 0; nt < 4; nt++)
                C[mt][nt] = __builtin_amdgcn_mfma_f32_16x16x32_f16(a[mt], b[nt],
                                                                   C[mt][nt], 0, 0, 0);
    }
    __syncthreads();
    // epilogue: relu + optional dinv scale; repack into As as [node][f] fp16
#pragma unroll
    for (int mt = 0; mt < 2; mt++) {
#pragma unroll
        for (int reg = 0; reg < 4; reg++) {
            int nd = m_base + mt * 16 + quad * 4 + reg;
            int node = node0 + nd;
            float dv = (scale_out && node < n) ? dinv[node] : 1.f;
#pragma unroll
            for (int nt = 0; nt < 4; nt++) {
                float v = fmaxf(C[mt][nt][reg], 0.f) * dv;
                As[nd * 72 + nt * 16 + nl] = __half_as_ushort(__float2half(v));
            }
        }
    }
    __syncthreads();
    // coalesced half2 store
    for (int i = t; i < 128 * 32; i += 256) {
        int nd = i >> 5, kp = i & 31;
        int node = node0 + nd;
        if (node < n) hpn[(size_t)node * 32 + kp] = *(const __half2*)&As[nd * 72 + 2 * kp];
    }
}

// ---------- y = h @ W2 + b2  (h fp16) ----------
__global__ void mlp_out(const __half* __restrict__ h, const float* __restrict__ W2,
                        const float* __restrict__ b2, float* __restrict__ y, int n) {
    __shared__ float hs[32 * HID];
    __shared__ float W2s[HID * DOUT];
    __shared__ float b2s[DOUT];
    int t = threadIdx.x;
    for (int i = t; i < HID * DOUT; i += 256) W2s[i] = W2[i];
    if (t < DOUT) b2s[t] = b2[t];
    int node0 = blockIdx.x * 32;
    for (int i = t; i < 32 * HID; i += 256) {
        int node = node0 + (i >> 6);
        hs[i] = (node < n) ? __half2float(h[(size_t)node0 * HID + i]) : 0.f;
    }
    __syncthreads();
    for (int idx = t; idx < 32 * DOUT; idx += 256) {
        int nloc = idx / DOUT, fo = idx % DOUT;
        int node = node0 + nloc;
        if (node >= n) continue;
        float dot = b2s[fo];
#pragma unroll 8
        for (int k = 0; k < HID; k++) dot += hs[nloc * HID + k] * W2s[k * DOUT + fo];
        y[(size_t)node * DOUT + fo] = dot;
    }
}

extern "C" void kernel_launch(void* const* d_in, const int* in_sizes, int n_in,
                              void* d_out, int out_size, void* d_ws, size_t ws_size,
                              hipStream_t stream) {
    const float*    x     = (const float*)d_in[0];
    const uint32_t* ei    = (const uint32_t*)d_in[1];
    const float*    W1    = (const float*)d_in[2];
    const float*    b1    = (const float*)d_in[3];
    const float*    convw = (const float*)d_in[4];
    const float*    W2    = (const float*)d_in[5];
    const float*    b2    = (const float*)d_in[6];
    float*          y     = (float*)d_out;

    int N = in_sizes[0] / DIN;
    int E = in_sizes[1] / 2;

    char* ws = (char*)d_ws;
    size_t off = 0;
    auto alloc = [&](size_t bytes) -> char* {
        char* p = ws + off;
        off = (off + bytes + 255) & ~(size_t)255;
        return p;
    };
    int*     flag      = (int*)alloc(4);
    int*     cnt       = (int*)alloc((size_t)N * 4);
    int*     row_start = (int*)alloc((size_t)N * 4);
    float*   dinv      = (float*)alloc((size_t)N * 4);
    int*     blocksum  = (int*)alloc(512 * 4);
    int*     pw        = (int*)alloc((size_t)E * 4);
    int*     csr_src   = (int*)alloc((size_t)E * 4);
    __half*  Bp        = (__half*)alloc((size_t)N_LAYERS * HID * HID * 2);
    __half*  h0h       = (__half*)alloc((size_t)N * HID * 2);
    __half2* aggb      = (__half2*)alloc((size_t)N * HID * 2);
    __half*  hpA       = (__half*)alloc((size_t)N * HID * 2);
    __half*  hpB       = (__half*)alloc((size_t)N * HID * 2);

    detect_i64<<<1, 64, 0, stream>>>(ei, flag);
    make_bp<<<N_LAYERS, 256, 0, stream>>>(convw, Bp);
    init_cnt<<<cdiv(N, 256), 256, 0, stream>>>(cnt, N);
    count_pos<<<cdiv(E, 256), 256, 0, stream>>>(ei, flag, cnt, pw, E);
    int nb = cdiv(N, 256);
    scan1<<<nb, 256, 0, stream>>>(cnt, row_start, blocksum, N);
    scan2<<<1, 512, 0, stream>>>(blocksum, nb);
    scan3<<<cdiv(N, 256), 256, 0, stream>>>(row_start, blocksum, N);
    compute_dinv<<<cdiv(N, 256), 256, 0, stream>>>(cnt, dinv, N);
    scatter_pos<<<cdiv(E, 256), 256, 0, stream>>>(ei, flag, row_start, pw, csr_src, E);

    mlp_in_v3<<<cdiv(N, MT), 256, 0, stream>>>(x, W1, b1, dinv, hpA, h0h, N);

    __half* cur = hpA;
    __half* nxt = hpB;
    for (int i = 0; i < N_LAYERS; i++) {
        int scale_out = (i < N_LAYERS - 1) ? 1 : 0;
        spmm_h2<<<cdiv(N, 4), 256, 0, stream>>>((const __half2*)cur, row_start, cnt,
                                                csr_src, dinv, aggb, N);
        layer_mfma<<<cdiv(N, 128), 256, 0, stream>>>(aggb, (const __half2*)h0h,
                                                     Bp + (size_t)i * HID * HID,
                                                     dinv, scale_out, (__half2*)nxt, N);
        __half* tmp = cur; cur = nxt; nxt = tmp;
    }
    mlp_out<<<cdiv(N, 32), 256, 0, stream>>>(cur, W2, b2, y, N);
}

// Round 8
// 778.557 us; speedup vs baseline: 3.8505x; 1.1246x over previous
//
#include <hip/hip_runtime.h>
#include <hip/hip_fp16.h>
#include <stdint.h>
#include <math.h>

#define HID 64
#define DIN 128
#define DOUT 40
#define N_LAYERS 8

typedef _Float16 half8 __attribute__((ext_vector_type(8)));
typedef float f32x4 __attribute__((ext_vector_type(4)));

static inline int cdiv(int a, int b) { return (a + b - 1) / b; }

// ---------- edge-index layout detection (int32 vs int64 storage) ----------
__global__ void detect_i64(const uint32_t* __restrict__ ei, int* __restrict__ flag) {
    int t = threadIdx.x;
    uint32_t w = ei[2 * t + 1];
    unsigned long long nz = __ballot(w != 0u);
    if (t == 0) *flag = (nz == 0ull) ? 1 : 0;
}

__device__ __forceinline__ int edge_src(const uint32_t* ei, int is64, int E, int e) {
    return is64 ? (int)ei[2 * e] : (int)ei[e];
}
__device__ __forceinline__ int edge_dst(const uint32_t* ei, int is64, int E, int e) {
    return is64 ? (int)ei[2 * (size_t)E + 2 * e] : (int)ei[(size_t)E + e];
}

// ---------- CSR construction (split-phase ticket) ----------
__global__ void init_cnt(int* __restrict__ cnt, int n) {
    int v = blockIdx.x * blockDim.x + threadIdx.x;
    if (v < n) cnt[v] = 0;
}

__global__ void count_pos(const uint32_t* __restrict__ ei, const int* __restrict__ flag,
                          int* __restrict__ cnt, int* __restrict__ pw, int E) {
    int e = blockIdx.x * blockDim.x + threadIdx.x;
    if (e >= E) return;
    int is64 = *flag;
    int d = edge_dst(ei, is64, E, e);
    pw[e] = atomicAdd(&cnt[d], 1);
}

__global__ void scan1(const int* __restrict__ cnt, int* __restrict__ row_start,
                      int* __restrict__ blocksum, int n) {
    __shared__ int sh[256];
    int t = threadIdx.x;
    int v = blockIdx.x * 256 + t;
    int val = (v < n) ? cnt[v] : 0;
    sh[t] = val;
    __syncthreads();
    for (int o = 1; o < 256; o <<= 1) {
        int y = (t >= o) ? sh[t - o] : 0;
        __syncthreads();
        sh[t] += y;
        __syncthreads();
    }
    if (v < n) row_start[v] = sh[t] - val;
    if (t == 255) blocksum[blockIdx.x] = sh[255];
}

__global__ void scan2(int* __restrict__ blocksum, int nb) {
    __shared__ int sh[512];
    int t = threadIdx.x;
    int val = (t < nb) ? blocksum[t] : 0;
    sh[t] = val;
    __syncthreads();
    for (int o = 1; o < 512; o <<= 1) {
        int y = (t >= o) ? sh[t - o] : 0;
        __syncthreads();
        sh[t] += y;
        __syncthreads();
    }
    if (t < nb) blocksum[t] = sh[t] - val;
}

__global__ void scan3(int* __restrict__ row_start, const int* __restrict__ blocksum, int n) {
    int v = blockIdx.x * 256 + threadIdx.x;
    if (v < n) row_start[v] += blocksum[v >> 8];
}

__global__ void compute_dinv(const int* __restrict__ cnt, float* __restrict__ dinv, int n) {
    int v = blockIdx.x * blockDim.x + threadIdx.x;
    if (v < n) dinv[v] = rsqrtf((float)(cnt[v] + 1));
}

__global__ void scatter_pos(const uint32_t* __restrict__ ei, const int* __restrict__ flag,
                            const int* __restrict__ row_start, const int* __restrict__ pw,
                            int* __restrict__ csr_src, int E) {
    int e = blockIdx.x * blockDim.x + threadIdx.x;
    if (e >= E) return;
    int is64 = *flag;
    int s = edge_src(ei, is64, E, e);
    int d = edge_dst(ei, is64, E, e);
    csr_src[row_start[d] + pw[e]] = s;
}

// ---------- Bp_i = fp16(beta_i * W_i + (1-beta_i) * I), stored transposed [n][k] ----
__global__ void make_bp(const float* __restrict__ convw, __half* __restrict__ Bp) {
    int i = blockIdx.x;
    float beta = logf(0.5f / (float)(i + 1) + 1.f);
    const float* W = convw + (size_t)i * HID * HID;
    __half* out = Bp + (size_t)i * HID * HID;
    for (int idx = threadIdx.x; idx < HID * HID; idx += blockDim.x) {
        int k = idx >> 6, nn = idx & 63;
        float v = beta * W[k * HID + nn] + ((k == nn) ? (1.f - beta) : 0.f);
        out[nn * HID + k] = __float2half(v);
    }
}

// ---------- W1h = fp16(W1^T) : [64 n][128 k] ----------
__global__ void make_w1t(const float* __restrict__ W1, __half* __restrict__ W1h) {
    for (int idx = threadIdx.x; idx < DIN * HID; idx += blockDim.x) {
        int nn = idx >> 7, k = idx & 127;
        W1h[nn * DIN + k] = __float2half(W1[k * HID + nn]);
    }
}

// ---------- MFMA input layer: h0h = fp16(relu(x@W1+b1)); hp = fp16(dinv*h0) ----------
// 128-node tile; A = fp16(x) [128][128] LDS, B = W1h [64][128] LDS
__global__ void __launch_bounds__(256) mlp_in_mfma(
        const float* __restrict__ x, const __half* __restrict__ W1h,
        const float* __restrict__ b1, const float* __restrict__ dinv,
        __half2* __restrict__ hp2, __half2* __restrict__ h0h2, int n) {
    __shared__ __align__(16) ushort Bs[64 * 136];    // [n][k] pad +8
    __shared__ __align__(16) ushort As[128 * 136];   // [node][k] pad +8; reused for out
    int t = threadIdx.x;
    // stage B
    {
        const __half2* W2 = (const __half2*)W1h;
        for (int i = t; i < 64 * 64; i += 256) {
            int bn = i >> 6, kp = i & 63;
            *(__half2*)&As[0] ; // no-op to keep alignment hints honest
            *(__half2*)&Bs[bn * 136 + 2 * kp] = W2[bn * 64 + kp];
        }
    }
    int node0 = blockIdx.x * 128;
    // stage A = fp16(x)
    {
        const float4* x4 = (const float4*)x;
        for (int i = t; i < 128 * 32; i += 256) {
            int nd = i >> 5, q = i & 31;
            int node = node0 + nd;
            float4 xv = (node < n) ? x4[(size_t)node * 32 + q]
                                   : make_float4(0.f, 0.f, 0.f, 0.f);
            *(__half2*)&As[nd * 136 + q * 4]     = __floats2half2_rn(xv.x, xv.y);
            *(__half2*)&As[nd * 136 + q * 4 + 2] = __floats2half2_rn(xv.z, xv.w);
        }
    }
    __syncthreads();
    int lane = t & 63, wv = t >> 6;
    int nl = lane & 15, quad = lane >> 4;
    int m_base = wv * 32;
    f32x4 C[2][4];
#pragma unroll
    for (int mt = 0; mt < 2; mt++)
#pragma unroll
        for (int nt = 0; nt < 4; nt++) C[mt][nt] = (f32x4)0.f;
#pragma unroll
    for (int kc = 0; kc < 4; kc++) {
        half8 a[2], b[4];
#pragma unroll
        for (int mt = 0; mt < 2; mt++)
            a[mt] = *(const half8*)&As[(m_base + mt * 16 + nl) * 136 + kc * 32 + quad * 8];
#pragma unroll
        for (int nt = 0; nt < 4; nt++)
            b[nt] = *(const half8*)&Bs[(nt * 16 + nl) * 136 + kc * 32 + quad * 8];
#pragma unroll
        for (int mt = 0; mt < 2; mt++)
#pragma unroll
            for (int nt = 0; nt < 4; nt++)
                C[mt][nt] = __builtin_amdgcn_mfma_f32_16x16x32_f16(a[mt], b[nt],
                                                                   C[mt][nt], 0, 0, 0);
    }
    __syncthreads();
    // epilogue: +b1, relu; repack into As as [node][f] (stride 72)
#pragma unroll
    for (int nt = 0; nt < 4; nt++) {
        float bias = b1[nt * 16 + nl];
#pragma unroll
        for (int mt = 0; mt < 2; mt++) {
#pragma unroll
            for (int reg = 0; reg < 4; reg++) {
                int nd = m_base + mt * 16 + quad * 4 + reg;
                float v = fmaxf(C[mt][nt][reg] + bias, 0.f);
                As[nd * 72 + nt * 16 + nl] = __half_as_ushort(__float2half(v));
            }
        }
    }
    __syncthreads();
    for (int i = t; i < 128 * 32; i += 256) {
        int nd = i >> 5, kp = i & 31;
        int node = node0 + nd;
        if (node < n) {
            __half2 h = *(const __half2*)&As[nd * 72 + 2 * kp];
            h0h2[(size_t)node * 32 + kp] = h;
            float dv = dinv[node];
            float2 f = __half22float2(h);
            hp2[(size_t)node * 32 + kp] = __floats2half2_rn(f.x * dv, f.y * dv);
        }
    }
}

// ---------- SpMM half2 v2: contiguous half-rows per group, 8/4/1 unroll tiers ----------
__global__ void spmm_h2(const __half2* __restrict__ hp2,
                        const int* __restrict__ row_start, const int* __restrict__ cnt,
                        const int* __restrict__ csr_src, const float* __restrict__ dinv,
                        __half2* __restrict__ agg, int n) {
    int v = (blockIdx.x * blockDim.x + threadIdx.x) >> 6;
    int lane = threadIdx.x & 63;
    if (v >= n) return;
    int f2 = lane & 31, g = lane >> 5;
    int j = row_start[v];
    int c = cnt[v];
    int h1 = (c + 1) >> 1;
    int e = j + (g ? h1 : 0);
    int end = g ? (j + c) : (j + h1);
    float ax = 0.f, ay = 0.f;
    if (g == 0) {
        float2 s = __half22float2(hp2[(size_t)v * 32 + f2]);
        ax = s.x; ay = s.y;
    }
    for (; e + 8 <= end; e += 8) {
        int s0 = csr_src[e],     s1 = csr_src[e + 1];
        int s2 = csr_src[e + 2], s3 = csr_src[e + 3];
        int s4 = csr_src[e + 4], s5 = csr_src[e + 5];
        int s6 = csr_src[e + 6], s7 = csr_src[e + 7];
        float2 f0 = __half22float2(hp2[(size_t)s0 * 32 + f2]);
        float2 f1 = __half22float2(hp2[(size_t)s1 * 32 + f2]);
        float2 f2v = __half22float2(hp2[(size_t)s2 * 32 + f2]);
        float2 f3 = __half22float2(hp2[(size_t)s3 * 32 + f2]);
        float2 f4 = __half22float2(hp2[(size_t)s4 * 32 + f2]);
        float2 f5 = __half22float2(hp2[(size_t)s5 * 32 + f2]);
        float2 f6 = __half22float2(hp2[(size_t)s6 * 32 + f2]);
        float2 f7 = __half22float2(hp2[(size_t)s7 * 32 + f2]);
        ax += ((f0.x + f1.x) + (f2v.x + f3.x)) + ((f4.x + f5.x) + (f6.x + f7.x));
        ay += ((f0.y + f1.y) + (f2v.y + f3.y)) + ((f4.y + f5.y) + (f6.y + f7.y));
    }
    if (e + 4 <= end) {
        int s0 = csr_src[e],     s1 = csr_src[e + 1];
        int s2 = csr_src[e + 2], s3 = csr_src[e + 3];
        float2 f0 = __half22float2(hp2[(size_t)s0 * 32 + f2]);
        float2 f1 = __half22float2(hp2[(size_t)s1 * 32 + f2]);
        float2 f2v = __half22float2(hp2[(size_t)s2 * 32 + f2]);
        float2 f3 = __half22float2(hp2[(size_t)s3 * 32 + f2]);
        ax += (f0.x + f1.x) + (f2v.x + f3.x);
        ay += (f0.y + f1.y) + (f2v.y + f3.y);
        e += 4;
    }
    for (; e < end; ++e) {
        float2 fv = __half22float2(hp2[(size_t)csr_src[e] * 32 + f2]);
        ax += fv.x; ay += fv.y;
    }
    ax += __shfl_xor(ax, 32);
    ay += __shfl_xor(ay, 32);
    if (g == 0) {
        float s = 0.9f * dinv[v];
        agg[(size_t)v * 32 + f2] = __floats2half2_rn(s * ax, s * ay);
    }
}

// ---------- MFMA dense layer: hpn = fp16((dinv?)*relu((agg + 0.1*h0) @ Bp)) ----------
__global__ void __launch_bounds__(256) layer_mfma(
        const __half2* __restrict__ agg, const __half2* __restrict__ h0h,
        const __half* __restrict__ Bp, const float* __restrict__ dinv,
        int scale_out, __half2* __restrict__ hpn, int n) {
    __shared__ __align__(16) ushort Bs[64 * 72];
    __shared__ __align__(16) ushort As[128 * 72];
    int t = threadIdx.x;
    {
        const __half2* B2 = (const __half2*)Bp;
        for (int i = t; i < 64 * 32; i += 256) {
            int bn = i >> 5, kp = i & 31;
            *(__half2*)&Bs[bn * 72 + 2 * kp] = B2[bn * 32 + kp];
        }
    }
    int node0 = blockIdx.x * 128;
    for (int i = t; i < 128 * 32; i += 256) {
        int nd = i >> 5, kp = i & 31;
        int node = node0 + nd;
        __half2 o;
        if (node < n) {
            float2 a = __half22float2(agg[(size_t)node * 32 + kp]);
            float2 h = __half22float2(h0h[(size_t)node * 32 + kp]);
            o = __floats2half2_rn(a.x + 0.1f * h.x, a.y + 0.1f * h.y);
        } else {
            o = __floats2half2_rn(0.f, 0.f);
        }
        *(__half2*)&As[nd * 72 + 2 * kp] = o;
    }
    __syncthreads();
    int lane = t & 63, wv = t >> 6;
    int nl = lane & 15, quad = lane >> 4;
    int m_base = wv * 32;
    f32x4 C[2][4];
#pragma unroll
    for (int mt = 0; mt < 2; mt++)
#pragma unroll
        for (int nt = 0; nt < 4; nt++) C[mt][nt] = (f32x4)0.f;
#pragma unroll
    for (int kc = 0; kc < 2; kc++) {
        half8 a[2], b[4];
#pragma unroll
        for (int mt = 0; mt < 2; mt++)
            a[mt] = *(const half8*)&As[(m_base + mt * 16 + nl) * 72 + kc * 32 + quad * 8];
#pragma unroll
        for (int nt = 0; nt < 4; nt++)
            b[nt] = *(const half8*)&Bs[(nt * 16 + nl) * 72 + kc * 32 + quad * 8];
#pragma unroll
        for (int mt = 0; mt < 2; mt++)
#pragma unroll
            for (int nt = 0; nt < 4; nt++)
                C[mt][nt] = __builtin_amdgcn_mfma_f32_16x16x32_f16(a[mt], b[nt],
                                                                   C[mt][nt], 0, 0, 0);
    }
    __syncthreads();
#pragma unroll
    for (int mt = 0; mt < 2; mt++) {
#pragma unroll
        for (int reg = 0; reg < 4; reg++) {
            int nd = m_base + mt * 16 + quad * 4 + reg;
            int node = node0 + nd;
            float dv = (scale_out && node < n) ? dinv[node] : 1.f;
#pragma unroll
            for (int nt = 0; nt < 4; nt++) {
                float v = fmaxf(C[mt][nt][reg], 0.f) * dv;
                As[nd * 72 + nt * 16 + nl] = __half_as_ushort(__float2half(v));
            }
        }
    }
    __syncthreads();
    for (int i = t; i < 128 * 32; i += 256) {
        int nd = i >> 5, kp = i & 31;
        int node = node0 + nd;
        if (node < n) hpn[(size_t)node * 32 + kp] = *(const __half2*)&As[nd * 72 + 2 * kp];
    }
}

// ---------- y = h @ W2 + b2  (h fp16) ----------
__global__ void mlp_out(const __half* __restrict__ h, const float* __restrict__ W2,
                        const float* __restrict__ b2, float* __restrict__ y, int n) {
    __shared__ float hs[32 * HID];
    __shared__ float W2s[HID * DOUT];
    __shared__ float b2s[DOUT];
    int t = threadIdx.x;
    for (int i = t; i < HID * DOUT; i += 256) W2s[i] = W2[i];
    if (t < DOUT) b2s[t] = b2[t];
    int node0 = blockIdx.x * 32;
    for (int i = t; i < 32 * HID; i += 256) {
        int node = node0 + (i >> 6);
        hs[i] = (node < n) ? __half2float(h[(size_t)node0 * HID + i]) : 0.f;
    }
    __syncthreads();
    for (int idx = t; idx < 32 * DOUT; idx += 256) {
        int nloc = idx / DOUT, fo = idx % DOUT;
        int node = node0 + nloc;
        if (node >= n) continue;
        float dot = b2s[fo];
#pragma unroll 8
        for (int k = 0; k < HID; k++) dot += hs[nloc * HID + k] * W2s[k * DOUT + fo];
        y[(size_t)node * DOUT + fo] = dot;
    }
}

extern "C" void kernel_launch(void* const* d_in, const int* in_sizes, int n_in,
                              void* d_out, int out_size, void* d_ws, size_t ws_size,
                              hipStream_t stream) {
    const float*    x     = (const float*)d_in[0];
    const uint32_t* ei    = (const uint32_t*)d_in[1];
    const float*    W1    = (const float*)d_in[2];
    const float*    b1    = (const float*)d_in[3];
    const float*    convw = (const float*)d_in[4];
    const float*    W2    = (const float*)d_in[5];
    const float*    b2    = (const float*)d_in[6];
    float*          y     = (float*)d_out;

    int N = in_sizes[0] / DIN;
    int E = in_sizes[1] / 2;

    char* ws = (char*)d_ws;
    size_t off = 0;
    auto alloc = [&](size_t bytes) -> char* {
        char* p = ws + off;
        off = (off + bytes + 255) & ~(size_t)255;
        return p;
    };
    int*     flag      = (int*)alloc(4);
    int*     cnt       = (int*)alloc((size_t)N * 4);
    int*     row_start = (int*)alloc((size_t)N * 4);
    float*   dinv      = (float*)alloc((size_t)N * 4);
    int*     blocksum  = (int*)alloc(512 * 4);
    int*     pw        = (int*)alloc((size_t)E * 4);
    int*     csr_src   = (int*)alloc((size_t)E * 4);
    __half*  Bp        = (__half*)alloc((size_t)N_LAYERS * HID * HID * 2);
    __half*  W1h       = (__half*)alloc((size_t)DIN * HID * 2);
    __half*  h0h       = (__half*)alloc((size_t)N * HID * 2);
    __half2* aggb      = (__half2*)alloc((size_t)N * HID * 2);
    __half*  hpA       = (__half*)alloc((size_t)N * HID * 2);
    __half*  hpB       = (__half*)alloc((size_t)N * HID * 2);

    detect_i64<<<1, 64, 0, stream>>>(ei, flag);
    make_bp<<<N_LAYERS, 256, 0, stream>>>(convw, Bp);
    make_w1t<<<1, 256, 0, stream>>>(W1, W1h);
    init_cnt<<<cdiv(N, 256), 256, 0, stream>>>(cnt, N);
    count_pos<<<cdiv(E, 256), 256, 0, stream>>>(ei, flag, cnt, pw, E);
    int nb = cdiv(N, 256);
    scan1<<<nb, 256, 0, stream>>>(cnt, row_start, blocksum, N);
    scan2<<<1, 512, 0, stream>>>(blocksum, nb);
    scan3<<<cdiv(N, 256), 256, 0, stream>>>(row_start, blocksum, N);
    compute_dinv<<<cdiv(N, 256), 256, 0, stream>>>(cnt, dinv, N);
    scatter_pos<<<cdiv(E, 256), 256, 0, stream>>>(ei, flag, row_start, pw, csr_src, E);

    mlp_in_mfma<<<cdiv(N, 128), 256, 0, stream>>>(x, W1h, b1, dinv,
                                                  (__half2*)hpA, (__half2*)h0h, N);

    __half* cur = hpA;
    __half* nxt = hpB;
    for (int i = 0; i < N_LAYERS; i++) {
        int scale_out = (i < N_LAYERS - 1) ? 1 : 0;
        spmm_h2<<<cdiv(N, 4), 256, 0, stream>>>((const __half2*)cur, row_start, cnt,
                                                csr_src, dinv, aggb, N);
        layer_mfma<<<cdiv(N, 128), 256, 0, stream>>>(aggb, (const __half2*)h0h,
                                                     Bp + (size_t)i * HID * HID,
                                                     dinv, scale_out, (__half2*)nxt, N);
        __half* tmp = cur; cur = nxt; nxt = tmp;
    }
    mlp_out<<<cdiv(N, 32), 256, 0, stream>>>(cur, W2, b2, y, N);
}